// Round 7
// baseline (40548.676 us; speedup 1.0000x reference)
//
#include <hip/hip_runtime.h>

#define T_FULL 1024
#define NBATCH 64
#define IDIM   512
#define NCH    256
#define GD     768
#define ODIM   3
#define NBG    4      // batch groups = rec blocks, 16 batches each

typedef _Float16 half8 __attribute__((ext_vector_type(8)));
typedef _Float16 half4 __attribute__((ext_vector_type(4)));
typedef float    floatx4 __attribute__((ext_vector_type(4)));

// workspace layout (bytes)
#define PP_OFF   1179648   // Wp: 3*48*8*64*16B = 1,179,648
#define WCB_OFF  1187840   // Pp: 8KB
#define HS_OFF   1200128   // Wcb: 12KB
#define XW_OFF   1376256   // hs: 128KB (+pad)

__device__ __forceinline__ float sigmoidf_(float x) { return 1.0f / (1.0f + __expf(-x)); }
__device__ __forceinline__ float tanhf_(float x)    { return 1.0f - 2.0f / (__expf(2.0f * x) + 1.0f); }
__device__ __forceinline__ floatx4 splat4(float v) { floatx4 r; r[0]=v; r[1]=v; r[2]=v; r[3]=v; return r; }

__device__ __forceinline__ half8 cvt8(const float* __restrict__ p) {
  floatx4 a = *(const floatx4*)p;
  floatx4 b = *(const floatx4*)(p + 4);
  half8 h;
  h[0]=(_Float16)a[0]; h[1]=(_Float16)a[1]; h[2]=(_Float16)a[2]; h[3]=(_Float16)a[3];
  h[4]=(_Float16)b[0]; h[5]=(_Float16)b[1]; h[6]=(_Float16)b[2]; h[7]=(_Float16)b[3];
  return h;
}

// ---------------------------------------------------------------------------
// One-time weight prep: f32 -> f16 MFMA B-fragment layout.
// Element offset = (m*48+pt)*4096 + ks*512 + lane*8, pt = (c>>4)*3 + g.
// Fragment (pt,ks,lane=(lq,lc)) = W[g*256 + (pt/3)*16+lc][ks*32+lq*8 .. +8].
// m: 0=w_hh0, 1=w_ih1, 2=w_hh1.  Pp: same frag layout for proj_w (3 rows).
// ---------------------------------------------------------------------------
__global__ __launch_bounds__(256)
void wprep_w(const float* __restrict__ w_hh0, const float* __restrict__ w_ih1,
             const float* __restrict__ w_hh1, const float* __restrict__ proj_w,
             _Float16* __restrict__ Wp, _Float16* __restrict__ Pp) {
  const int idx = blockIdx.x * 256 + threadIdx.x;
  if (idx < 73728) {
    const int m = idx / 24576, r = idx % 24576;
    const int pt = r / 512, r2 = r % 512;
    const int ks = r2 / 64, lane = r2 % 64;
    const int lq = lane >> 4, lc = lane & 15;
    const int c = (pt / 3) * 16 + lc, g = pt % 3;
    const float* src = (m == 0 ? w_hh0 : (m == 1 ? w_ih1 : w_hh1))
                       + (size_t)(g * NCH + c) * NCH + ks * 32 + lq * 8;
    *(half8*)(Wp + (size_t)idx * 8) = cvt8(src);
  } else if (idx < 74240) {
    const int j = idx - 73728;
    const int ks = j >> 6, lane = j & 63;
    const int lq = lane >> 4, lc = lane & 15;
    half8 v;
    if (lc < 3) v = cvt8(proj_w + lc * NCH + ks * 32 + lq * 8);
    else { for (int k = 0; k < 8; ++k) v[k] = (_Float16)0.f; }
    *(half8*)(Pp + (size_t)j * 8) = v;
  }
}

// Wcb[prow][4] = {Wce0, Wce1, Wce2, b_ih0 + W_ih0[:,512:]@embed_b}, prow=pt*16+lc
__global__ __launch_bounds__(256)
void wprep_c(const float* __restrict__ w_ih0, const float* __restrict__ embed_w,
             const float* __restrict__ embed_b, const float* __restrict__ b_ih0,
             float* __restrict__ Wcb) {
  const int prow = blockIdx.x * 256 + threadIdx.x;
  if (prow >= 768) return;
  const int pt = prow >> 4, lcc = prow & 15;
  const int c = (pt / 3) * 16 + lcc, g = pt % 3;
  const int srow = g * NCH + c;
  const float* wr = w_ih0 + (size_t)srow * GD + IDIM;
  float a0 = 0.f, a1 = 0.f, a2 = 0.f, ab = b_ih0[srow];
  for (int k = 0; k < NCH; ++k) {
    const float w = wr[k];
    a0 += w * embed_w[k * 3 + 0];
    a1 += w * embed_w[k * 3 + 1];
    a2 += w * embed_w[k * 3 + 2];
    ab += w * embed_b[k];
  }
  Wcb[prow * 4 + 0] = a0; Wcb[prow * 4 + 1] = a1;
  Wcb[prow * 4 + 2] = a2; Wcb[prow * 4 + 3] = ab;
}

// ---------------------------------------------------------------------------
// Precompute GEMM (k<512 of layer-0 gates).
// Store layout: Xw[((t*4 + bg)*48 + pt)*256 + (c&15)*16 + (b&15)]  (f16)
// ---------------------------------------------------------------------------
__global__ __launch_bounds__(256)
void xw_gemm(const float* __restrict__ x, const float* __restrict__ w_ih0,
             _Float16* __restrict__ Xw, int t0, int Tc) {
  __shared__ _Float16 As[128 * 32];
  __shared__ _Float16 Bs[128 * 32];
  const int tid  = threadIdx.x;
  const int lane = tid & 63;
  const int wave = tid >> 6;
  const int lq = lane >> 4, lc = lane & 15;
  const int wm = wave >> 1, wn = wave & 1;

  const int sr = tid >> 1;
  const int sh = (tid & 1) * 16;
  const int m  = blockIdx.x * 128 + sr;
  const float* arow = x + ((size_t)(m & 63) * T_FULL + (size_t)(t0 + (m >> 6))) * IDIM;
  const float* brow = w_ih0 + (size_t)(blockIdx.y * 128 + sr) * GD;

  floatx4 acc[4][4];
  #pragma unroll
  for (int i = 0; i < 4; ++i)
    #pragma unroll
    for (int j = 0; j < 4; ++j) acc[i][j] = splat4(0.f);

  for (int kk = 0; kk < IDIM; kk += 32) {
    __syncthreads();
    #pragma unroll
    for (int kb = 0; kb < 2; ++kb) {
      const int k0  = sh + kb * 8;
      const int gis = (k0 >> 3) ^ ((sr >> 2) & 3);
      *(half8*)((char*)As + sr * 64 + gis * 16) = cvt8(arow + kk + k0);
      *(half8*)((char*)Bs + sr * 64 + gis * 16) = cvt8(brow + kk + k0);
    }
    __syncthreads();
    half8 af[4], bf[4];
    #pragma unroll
    for (int ms = 0; ms < 4; ++ms) {
      const int r = wm * 64 + ms * 16 + lc;
      af[ms] = *(const half8*)((char*)As + r * 64 + ((lq ^ ((r >> 2) & 3)) * 16));
    }
    #pragma unroll
    for (int ns = 0; ns < 4; ++ns) {
      const int r = wn * 64 + ns * 16 + lc;
      bf[ns] = *(const half8*)((char*)Bs + r * 64 + ((lq ^ ((r >> 2) & 3)) * 16));
    }
    #pragma unroll
    for (int ms = 0; ms < 4; ++ms)
      #pragma unroll
      for (int ns = 0; ns < 4; ++ns)
        acc[ms][ns] = __builtin_amdgcn_mfma_f32_16x16x32_f16(af[ms], bf[ns], acc[ms][ns], 0, 0, 0);
  }

  #pragma unroll
  for (int ms = 0; ms < 4; ++ms)
    #pragma unroll
    for (int ns = 0; ns < 4; ++ns)
      #pragma unroll
      for (int q = 0; q < 4; ++q) {
        const int mloc = blockIdx.x * 128 + wm * 64 + ms * 16 + lq * 4 + q;
        const int gp   = blockIdx.y * 128 + wn * 64 + ns * 16 + lc;
        const int t = mloc >> 6, b = mloc & 63;
        const int g = gp >> 8, c = gp & 255;
        const int pt = (c >> 4) * 3 + g;
        Xw[(((size_t)t * NBG + (b >> 4)) * 48 + pt) * 256 + (c & 15) * 16 + (b & 15)]
            = (_Float16)acc[ms][ns][q];
      }
}

// ---------------------------------------------------------------------------
// Zero-sync recurrent kernel: 4 blocks x 1024 threads (16 waves). Block bg
// owns batches [bg*16, +16); wave w owns channels [w*16, +16) and holds ALL
// its weight fragments in registers (288 VGPR). h exchanged via swizzled LDS,
// v broadcast via LDS. 3 __syncthreads per step; no cross-block comms.
// ---------------------------------------------------------------------------
__global__ __launch_bounds__(1024, 4)
void rec_r(const _Float16* __restrict__ Wp, const _Float16* __restrict__ Pp,
           const float* __restrict__ Wcb,
           const float* __restrict__ b_hh0, const float* __restrict__ b_ih1,
           const float* __restrict__ b_hh1, const float* __restrict__ proj_b,
           const _Float16* __restrict__ Xw, float* __restrict__ out,
           float* __restrict__ hs, int t0, int Tc, int lastChunk) {
  __shared__ __align__(16) _Float16 hl[2][2][4096]; // [layer][parity][16b x 256ch]
  __shared__ __align__(16) float v_lds[64];         // [16 b][4] (j<3 used)
  const int tid  = threadIdx.x;
  const int wave = tid >> 6;           // 0..15 = channel tile
  const int lane = tid & 63;
  const int lq = lane >> 4, lc = lane & 15;
  const int bg = blockIdx.x;
  const int ch = wave * 16 + lc;

  // swizzled LDS byte offset: row b (512B), channel k -> (k*2) ^ ((b&7)<<4)
  #define HBYTE(b, k) ((b) * 512 + (((k) * 2) ^ (((b) & 7) << 4)))
  #define LDA(layer, par, ks) \
    (*(const half8*)((const char*)(&hl[layer][par][0]) + lc * 512 + ((((ks) * 64) + lq * 16) ^ ((lc & 7) << 4))))

  // ---- weights into registers (one-time): this wave's 3 pt-tiles per matrix
  half8 W0[3][8], W1[3][8], W2[3][8], Pj[8];
  #pragma unroll
  for (int g = 0; g < 3; ++g)
    #pragma unroll
    for (int ks = 0; ks < 8; ++ks) {
      const size_t base = ((size_t)(wave * 3 + g) * 512 + ks * 64 + lane) * 8;
      W0[g][ks] = *(const half8*)(Wp + base);            // w_hh0
      W1[g][ks] = *(const half8*)(Wp + 196608 + base);   // w_ih1
      W2[g][ks] = *(const half8*)(Wp + 393216 + base);   // w_hh1
    }
  #pragma unroll
  for (int ks = 0; ks < 8; ++ks)
    Pj[ks] = *(const half8*)(Pp + ((size_t)ks * 64 + lane) * 8);

  // ---- folded constants
  float wcb[3][4], bh0c[3], bi1c[3], bh1c[3];
  #pragma unroll
  for (int g = 0; g < 3; ++g) {
    floatx4 t = *(const floatx4*)(Wcb + ((size_t)((wave * 3 + g) * 16 + lc)) * 4);
    wcb[g][0] = t[0]; wcb[g][1] = t[1]; wcb[g][2] = t[2]; wcb[g][3] = t[3];
    const int srow = g * NCH + ch;
    bh0c[g] = b_hh0[srow]; bi1c[g] = b_ih1[srow]; bh1c[g] = b_hh1[srow];
  }
  const float pb = (lc < 3) ? proj_b[lc] : 0.f;

  // ---- state (batch = lq*4+q of this block's 16)
  float h0st[4] = {0.f,0.f,0.f,0.f};
  float h1st[4] = {0.f,0.f,0.f,0.f};
  if (t0 > 0) {
    #pragma unroll
    for (int q = 0; q < 4; ++q) {
      h0st[q] = hs[((size_t)(bg * 2 + 0) * 16 + lq * 4 + q) * NCH + ch];
      h1st[q] = hs[((size_t)(bg * 2 + 1) * 16 + lq * 4 + q) * NCH + ch];
    }
  }
  const int pInit = (t0 & 1) ^ 1;
  #pragma unroll
  for (int q = 0; q < 4; ++q) {
    const int b = lq * 4 + q;
    *(_Float16*)((char*)(&hl[0][pInit][0]) + HBYTE(b, ch)) = (_Float16)h0st[q];
    *(_Float16*)((char*)(&hl[1][pInit][0]) + HBYTE(b, ch)) = (_Float16)h1st[q];
  }
  __syncthreads();

  for (int lt = 0; lt < Tc; ++lt) {
    const int gt = t0 + lt;
    const int rp = (gt & 1) ^ 1;
    const int wp = gt & 1;

    // ======== PHASE 1 ========
    const _Float16* xb = Xw + ((((size_t)lt * NBG + bg) * 48 + wave * 3) * 256)
                         + lc * 16 + lq * 4;
    half4 xwv[3];
    #pragma unroll
    for (int g = 0; g < 3; ++g) xwv[g] = *(const half4*)(xb + g * 256);

    half8 A1f[8], A0f[8];
    #pragma unroll
    for (int ks = 0; ks < 8; ++ks) { A1f[ks] = LDA(1, rp, ks); A0f[ks] = LDA(0, rp, ks); }

    // wave 0: v(t-1) from h1(t-1), broadcast + output write
    if (wave == 0 && gt > 0) {
      floatx4 av = splat4(pb);
      #pragma unroll
      for (int ks = 0; ks < 8; ++ks)
        av = __builtin_amdgcn_mfma_f32_16x16x32_f16(A1f[ks], Pj[ks], av, 0, 0, 0);
      #pragma unroll
      for (int q = 0; q < 4; ++q) {
        if (lc < 3) {
          const float sv = sigmoidf_(av[q]);
          v_lds[(lq * 4 + q) * 4 + lc] = sv;
          out[((size_t)(bg * 16 + lq * 4 + q) * T_FULL + (gt - 1)) * ODIM + lc] = sv;
        }
      }
    }

    // gh1 (persists to phase 2) and gh0
    floatx4 ag1[3], ag0[3];
    #pragma unroll
    for (int g = 0; g < 3; ++g) { ag1[g] = splat4(bh1c[g]); ag0[g] = splat4(bh0c[g]); }
    #pragma unroll
    for (int g = 0; g < 3; ++g)
      #pragma unroll
      for (int ks = 0; ks < 8; ++ks)
        ag1[g] = __builtin_amdgcn_mfma_f32_16x16x32_f16(A1f[ks], W2[g][ks], ag1[g], 0, 0, 0);
    #pragma unroll
    for (int g = 0; g < 3; ++g)
      #pragma unroll
      for (int ks = 0; ks < 8; ++ks)
        ag0[g] = __builtin_amdgcn_mfma_f32_16x16x32_f16(A0f[ks], W0[g][ks], ag0[g], 0, 0, 0);

    __syncthreads();   // barrier 1: v_lds ready

    floatx4 v4[4];
    if (gt == 0) {
      #pragma unroll
      for (int q = 0; q < 4; ++q) v4[q] = splat4(0.f);
    } else {
      #pragma unroll
      for (int q = 0; q < 4; ++q) v4[q] = *(const floatx4*)(&v_lds[(lq * 4 + q) * 4]);
    }

    // layer-0 combine, publish h0(t)
    #pragma unroll
    for (int q = 0; q < 4; ++q) {
      const float ir = (float)xwv[0][q] + wcb[0][3]
                       + v4[q][0] * wcb[0][0] + v4[q][1] * wcb[0][1] + v4[q][2] * wcb[0][2];
      const float iz = (float)xwv[1][q] + wcb[1][3]
                       + v4[q][0] * wcb[1][0] + v4[q][1] * wcb[1][1] + v4[q][2] * wcb[1][2];
      const float in_ = (float)xwv[2][q] + wcb[2][3]
                       + v4[q][0] * wcb[2][0] + v4[q][1] * wcb[2][1] + v4[q][2] * wcb[2][2];
      const float r = sigmoidf_(ir + ag0[0][q]);
      const float z = sigmoidf_(iz + ag0[1][q]);
      const float n = tanhf_(in_ + r * ag0[2][q]);
      const float h0n = (1.f - z) * n + z * h0st[q];
      h0st[q] = h0n;
      *(_Float16*)((char*)(&hl[0][wp][0]) + HBYTE(lq * 4 + q, ch)) = (_Float16)h0n;
    }
    __syncthreads();   // barrier 2: h0(t) visible

    // ======== PHASE 2 ========
    half8 A0n[8];
    #pragma unroll
    for (int ks = 0; ks < 8; ++ks) A0n[ks] = LDA(0, wp, ks);

    floatx4 ai[3];
    #pragma unroll
    for (int g = 0; g < 3; ++g) ai[g] = splat4(bi1c[g]);
    #pragma unroll
    for (int g = 0; g < 3; ++g)
      #pragma unroll
      for (int ks = 0; ks < 8; ++ks)
        ai[g] = __builtin_amdgcn_mfma_f32_16x16x32_f16(A0n[ks], W1[g][ks], ai[g], 0, 0, 0);

    #pragma unroll
    for (int q = 0; q < 4; ++q) {
      const float r = sigmoidf_(ai[0][q] + ag1[0][q]);
      const float z = sigmoidf_(ai[1][q] + ag1[1][q]);
      const float n = tanhf_(ai[2][q] + r * ag1[2][q]);
      const float h1n = (1.f - z) * n + z * h1st[q];
      h1st[q] = h1n;
      *(_Float16*)((char*)(&hl[1][wp][0]) + HBYTE(lq * 4 + q, ch)) = (_Float16)h1n;
    }
    __syncthreads();   // barrier 3: h1(t) visible for next step
  }

  // tail: v(T-1) from final h1
  if (lastChunk && wave == 0) {
    const int fp = (t0 + Tc - 1) & 1;
    floatx4 av = splat4(pb);
    #pragma unroll
    for (int ks = 0; ks < 8; ++ks)
      av = __builtin_amdgcn_mfma_f32_16x16x32_f16(LDA(1, fp, ks), Pj[ks], av, 0, 0, 0);
    if (lc < 3) {
      #pragma unroll
      for (int q = 0; q < 4; ++q)
        out[((size_t)(bg * 16 + lq * 4 + q) * T_FULL + (T_FULL - 1)) * ODIM + lc]
            = sigmoidf_(av[q]);
    }
  }

  // save state for next chunk (kernel boundary = coherent)
  #pragma unroll
  for (int q = 0; q < 4; ++q) {
    hs[((size_t)(bg * 2 + 0) * 16 + lq * 4 + q) * NCH + ch] = h0st[q];
    hs[((size_t)(bg * 2 + 1) * 16 + lq * 4 + q) * NCH + ch] = h1st[q];
  }
  #undef HBYTE
  #undef LDA
}

extern "C" void kernel_launch(void* const* d_in, const int* in_sizes, int n_in,
                              void* d_out, int out_size, void* d_ws, size_t ws_size,
                              hipStream_t stream) {
  const float* x       = (const float*)d_in[0];
  const float* embed_w = (const float*)d_in[1];
  const float* embed_b = (const float*)d_in[2];
  const float* w_ih0   = (const float*)d_in[3];
  const float* w_hh0   = (const float*)d_in[4];
  const float* b_ih0   = (const float*)d_in[5];
  const float* b_hh0   = (const float*)d_in[6];
  const float* w_ih1   = (const float*)d_in[7];
  const float* w_hh1   = (const float*)d_in[8];
  const float* b_ih1   = (const float*)d_in[9];
  const float* b_hh1   = (const float*)d_in[10];
  const float* proj_w  = (const float*)d_in[11];
  const float* proj_b  = (const float*)d_in[12];
  float* out = (float*)d_out;

  char* ws = (char*)d_ws;
  _Float16* Wp  = (_Float16*)ws;
  _Float16* Pp  = (_Float16*)(ws + PP_OFF);
  float*    Wcb = (float*)(ws + WCB_OFF);
  float*    hs  = (float*)(ws + HS_OFF);
  _Float16* Xw  = (_Float16*)(ws + XW_OFF);

  wprep_w<<<290, 256, 0, stream>>>(w_hh0, w_ih1, w_hh1, proj_w, Wp, Pp);
  wprep_c<<<3, 256, 0, stream>>>(w_ih0, embed_w, embed_b, b_ih0, Wcb);

  const size_t per_t = (size_t)NBATCH * GD * sizeof(_Float16);  // 98304 B
  size_t xw_avail = (ws_size > XW_OFF) ? (ws_size - XW_OFF) : 0;
  long maxTc = (long)(xw_avail / per_t);
  int Tc = 2;
  while ((long)Tc * 2 <= maxTc && Tc * 2 <= T_FULL) Tc *= 2;

  for (int t0 = 0; t0 < T_FULL; t0 += Tc) {
    dim3 g1(Tc * NBATCH / 128, GD / 128);
    xw_gemm<<<g1, 256, 0, stream>>>(x, w_ih0, Xw, t0, Tc);
    rec_r<<<NBG, 1024, 0, stream>>>(Wp, Pp, Wcb, b_hh0, b_ih1, b_hh1, proj_b,
                                    Xw, out, hs, t0, Tc,
                                    (t0 + Tc) >= T_FULL ? 1 : 0);
  }
}

// Round 8
// 37227.792 us; speedup vs baseline: 1.0892x; 1.0892x over previous
//
#include <hip/hip_runtime.h>

#define T_FULL 1024
#define NBATCH 64
#define IDIM   512
#define NCH    256
#define GD     768
#define ODIM   3
#define NBG    4      // batch groups = rec blocks, 16 batches each

typedef _Float16 half8 __attribute__((ext_vector_type(8)));
typedef _Float16 half4 __attribute__((ext_vector_type(4)));
typedef float    floatx4 __attribute__((ext_vector_type(4)));

// workspace layout (bytes)
#define PP_OFF   1179648   // Wp: 3*48*8*64*16B = 1,179,648
#define WCB_OFF  1187840   // Pp: 8KB
#define HS_OFF   1200128   // Wcb: 12KB
#define XW_OFF   1376256   // hs: 128KB (+pad)

__device__ __forceinline__ float sigmoidf_(float x) { return 1.0f / (1.0f + __expf(-x)); }
__device__ __forceinline__ float tanhf_(float x)    { return 1.0f - 2.0f / (__expf(2.0f * x) + 1.0f); }
__device__ __forceinline__ floatx4 splat4(float v) { floatx4 r; r[0]=v; r[1]=v; r[2]=v; r[3]=v; return r; }

__device__ __forceinline__ half8 cvt8(const float* __restrict__ p) {
  floatx4 a = *(const floatx4*)p;
  floatx4 b = *(const floatx4*)(p + 4);
  half8 h;
  h[0]=(_Float16)a[0]; h[1]=(_Float16)a[1]; h[2]=(_Float16)a[2]; h[3]=(_Float16)a[3];
  h[4]=(_Float16)b[0]; h[5]=(_Float16)b[1]; h[6]=(_Float16)b[2]; h[7]=(_Float16)b[3];
  return h;
}

// ---------------------------------------------------------------------------
// One-time weight prep: f32 -> f16 MFMA B-fragment layout.
// Element offset = (m*48+pt)*4096 + ks*512 + lane*8, pt = (c>>4)*3 + g.
// Fragment (pt,ks,lane=(lq,lc)) = W[g*256 + (pt/3)*16+lc][ks*32+lq*8 .. +8].
// m: 0=w_hh0, 1=w_ih1, 2=w_hh1.  Pp: same frag layout for proj_w (3 rows).
// ---------------------------------------------------------------------------
__global__ __launch_bounds__(256)
void wprep_w(const float* __restrict__ w_hh0, const float* __restrict__ w_ih1,
             const float* __restrict__ w_hh1, const float* __restrict__ proj_w,
             _Float16* __restrict__ Wp, _Float16* __restrict__ Pp) {
  const int idx = blockIdx.x * 256 + threadIdx.x;
  if (idx < 73728) {
    const int m = idx / 24576, r = idx % 24576;
    const int pt = r / 512, r2 = r % 512;
    const int ks = r2 / 64, lane = r2 % 64;
    const int lq = lane >> 4, lc = lane & 15;
    const int c = (pt / 3) * 16 + lc, g = pt % 3;
    const float* src = (m == 0 ? w_hh0 : (m == 1 ? w_ih1 : w_hh1))
                       + (size_t)(g * NCH + c) * NCH + ks * 32 + lq * 8;
    *(half8*)(Wp + (size_t)idx * 8) = cvt8(src);
  } else if (idx < 74240) {
    const int j = idx - 73728;
    const int ks = j >> 6, lane = j & 63;
    const int lq = lane >> 4, lc = lane & 15;
    half8 v;
    if (lc < 3) v = cvt8(proj_w + lc * NCH + ks * 32 + lq * 8);
    else { for (int k = 0; k < 8; ++k) v[k] = (_Float16)0.f; }
    *(half8*)(Pp + (size_t)j * 8) = v;
  }
}

// Wcb[prow][4] = {Wce0, Wce1, Wce2, b_ih0 + W_ih0[:,512:]@embed_b}, prow=pt*16+lc
__global__ __launch_bounds__(256)
void wprep_c(const float* __restrict__ w_ih0, const float* __restrict__ embed_w,
             const float* __restrict__ embed_b, const float* __restrict__ b_ih0,
             float* __restrict__ Wcb) {
  const int prow = blockIdx.x * 256 + threadIdx.x;
  if (prow >= 768) return;
  const int pt = prow >> 4, lcc = prow & 15;
  const int c = (pt / 3) * 16 + lcc, g = pt % 3;
  const int srow = g * NCH + c;
  const float* wr = w_ih0 + (size_t)srow * GD + IDIM;
  float a0 = 0.f, a1 = 0.f, a2 = 0.f, ab = b_ih0[srow];
  for (int k = 0; k < NCH; ++k) {
    const float w = wr[k];
    a0 += w * embed_w[k * 3 + 0];
    a1 += w * embed_w[k * 3 + 1];
    a2 += w * embed_w[k * 3 + 2];
    ab += w * embed_b[k];
  }
  Wcb[prow * 4 + 0] = a0; Wcb[prow * 4 + 1] = a1;
  Wcb[prow * 4 + 2] = a2; Wcb[prow * 4 + 3] = ab;
}

// ---------------------------------------------------------------------------
// Precompute GEMM (k<512 of layer-0 gates).
// Store layout: Xw[((t*4 + bg)*48 + pt)*256 + (c&15)*16 + (b&15)]  (f16)
// ---------------------------------------------------------------------------
__global__ __launch_bounds__(256)
void xw_gemm(const float* __restrict__ x, const float* __restrict__ w_ih0,
             _Float16* __restrict__ Xw, int t0, int Tc) {
  __shared__ _Float16 As[128 * 32];
  __shared__ _Float16 Bs[128 * 32];
  const int tid  = threadIdx.x;
  const int lane = tid & 63;
  const int wave = tid >> 6;
  const int lq = lane >> 4, lc = lane & 15;
  const int wm = wave >> 1, wn = wave & 1;

  const int sr = tid >> 1;
  const int sh = (tid & 1) * 16;
  const int m  = blockIdx.x * 128 + sr;
  const float* arow = x + ((size_t)(m & 63) * T_FULL + (size_t)(t0 + (m >> 6))) * IDIM;
  const float* brow = w_ih0 + (size_t)(blockIdx.y * 128 + sr) * GD;

  floatx4 acc[4][4];
  #pragma unroll
  for (int i = 0; i < 4; ++i)
    #pragma unroll
    for (int j = 0; j < 4; ++j) acc[i][j] = splat4(0.f);

  for (int kk = 0; kk < IDIM; kk += 32) {
    __syncthreads();
    #pragma unroll
    for (int kb = 0; kb < 2; ++kb) {
      const int k0  = sh + kb * 8;
      const int gis = (k0 >> 3) ^ ((sr >> 2) & 3);
      *(half8*)((char*)As + sr * 64 + gis * 16) = cvt8(arow + kk + k0);
      *(half8*)((char*)Bs + sr * 64 + gis * 16) = cvt8(brow + kk + k0);
    }
    __syncthreads();
    half8 af[4], bf[4];
    #pragma unroll
    for (int ms = 0; ms < 4; ++ms) {
      const int r = wm * 64 + ms * 16 + lc;
      af[ms] = *(const half8*)((char*)As + r * 64 + ((lq ^ ((r >> 2) & 3)) * 16));
    }
    #pragma unroll
    for (int ns = 0; ns < 4; ++ns) {
      const int r = wn * 64 + ns * 16 + lc;
      bf[ns] = *(const half8*)((char*)Bs + r * 64 + ((lq ^ ((r >> 2) & 3)) * 16));
    }
    #pragma unroll
    for (int ms = 0; ms < 4; ++ms)
      #pragma unroll
      for (int ns = 0; ns < 4; ++ns)
        acc[ms][ns] = __builtin_amdgcn_mfma_f32_16x16x32_f16(af[ms], bf[ns], acc[ms][ns], 0, 0, 0);
  }

  #pragma unroll
  for (int ms = 0; ms < 4; ++ms)
    #pragma unroll
    for (int ns = 0; ns < 4; ++ns)
      #pragma unroll
      for (int q = 0; q < 4; ++q) {
        const int mloc = blockIdx.x * 128 + wm * 64 + ms * 16 + lq * 4 + q;
        const int gp   = blockIdx.y * 128 + wn * 64 + ns * 16 + lc;
        const int t = mloc >> 6, b = mloc & 63;
        const int g = gp >> 8, c = gp & 255;
        const int pt = (c >> 4) * 3 + g;
        Xw[(((size_t)t * NBG + (b >> 4)) * 48 + pt) * 256 + (c & 15) * 16 + (b & 15)]
            = (_Float16)acc[ms][ns][q];
      }
}

// ---------------------------------------------------------------------------
// Zero-sync recurrent kernel: 4 blocks x 512 threads (8 waves, 1 block/CU,
// <=256 VGPR/wave). Block bg owns batches [bg*16,+16); wave owns 32 channels
// (2 ct-tiles x 3 gates = 6 pt-tiles/matrix). Weights streamed from L2 every
// step via 2-deep ping-pong prefetch chain over 18 tiles/step. h exchanged
// via swizzled LDS, 2 __syncthreads/step, no cross-block comms.
// ---------------------------------------------------------------------------
__global__ __launch_bounds__(512, 1)
void rec_s(const _Float16* __restrict__ Wp, const _Float16* __restrict__ Pp,
           const float* __restrict__ Wcb,
           const float* __restrict__ b_hh0, const float* __restrict__ b_ih1,
           const float* __restrict__ b_hh1, const float* __restrict__ proj_b,
           const _Float16* __restrict__ Xw, float* __restrict__ out,
           float* __restrict__ hs, int t0, int Tc, int lastChunk) {
  __shared__ __align__(16) _Float16 hl[2][2][4096]; // [layer][parity][16b x 256ch]
  const int tid  = threadIdx.x;
  const int wave = tid >> 6;           // 0..7: channels [wave*32, +32)
  const int lane = tid & 63;
  const int lq = lane >> 4, lc = lane & 15;
  const int bg = blockIdx.x;

  #define HBYTE(b, k) ((b) * 512 + (((k) * 2) ^ (((b) & 7) << 4)))
  #define LDA(layer, par, ks) \
    (*(const half8*)((const char*)(&hl[layer][par][0]) + lc * 512 + ((((ks) * 64) + lq * 16) ^ ((lc & 7) << 4))))

  // stream bases: matrix m at m*196608 elems; wave's 6 pt-tiles start at wave*6
  const _Float16* w0b = Wp +          ((size_t)(wave * 6) * 4096) + lane * 8;  // w_hh0
  const _Float16* w1b = Wp + 196608 + ((size_t)(wave * 6) * 4096) + lane * 8;  // w_ih1
  const _Float16* w2b = Wp + 393216 + ((size_t)(wave * 6) * 4096) + lane * 8;  // w_hh1

  // proj fragments resident (same for all waves)
  half8 Pj[8];
  #pragma unroll
  for (int ks = 0; ks < 8; ++ks) Pj[ks] = *(const half8*)(Pp + ks * 512 + lane * 8);

  // ---- folded constants: ct in {0,1}, ch = (wave*2+ct)*16 + lc
  int ch[2];
  float wcb[2][3][4], bh0c[2][3], bi1c[2][3], bh1c[2][3];
  #pragma unroll
  for (int ct = 0; ct < 2; ++ct) {
    ch[ct] = (wave * 2 + ct) * 16 + lc;
    #pragma unroll
    for (int g = 0; g < 3; ++g) {
      const int prow = ((wave * 2 + ct) * 3 + g) * 16 + lc;
      floatx4 t = *(const floatx4*)(Wcb + prow * 4);
      wcb[ct][g][0] = t[0]; wcb[ct][g][1] = t[1]; wcb[ct][g][2] = t[2]; wcb[ct][g][3] = t[3];
      const int srow = g * NCH + ch[ct];
      bh0c[ct][g] = b_hh0[srow]; bi1c[ct][g] = b_ih1[srow]; bh1c[ct][g] = b_hh1[srow];
    }
  }
  const float pb = (lc < 3) ? proj_b[lc] : 0.f;

  // ---- state
  float h0st[2][4] = {{0.f,0.f,0.f,0.f},{0.f,0.f,0.f,0.f}};
  float h1st[2][4] = {{0.f,0.f,0.f,0.f},{0.f,0.f,0.f,0.f}};
  if (t0 > 0) {
    #pragma unroll
    for (int ct = 0; ct < 2; ++ct)
      #pragma unroll
      for (int q = 0; q < 4; ++q) {
        h0st[ct][q] = hs[((size_t)(bg * 2 + 0) * 16 + lq * 4 + q) * NCH + ch[ct]];
        h1st[ct][q] = hs[((size_t)(bg * 2 + 1) * 16 + lq * 4 + q) * NCH + ch[ct]];
      }
  }
  const int pInit = (t0 & 1) ^ 1;
  #pragma unroll
  for (int ct = 0; ct < 2; ++ct)
    #pragma unroll
    for (int q = 0; q < 4; ++q) {
      const int b = lq * 4 + q;
      *(_Float16*)((char*)(&hl[0][pInit][0]) + HBYTE(b, ch[ct])) = (_Float16)h0st[ct][q];
      *(_Float16*)((char*)(&hl[1][pInit][0]) + HBYTE(b, ch[ct])) = (_Float16)h1st[ct][q];
    }
  __syncthreads();

  // ping-pong tile buffers; tile chain per step: W2[0..5] W0[0..5] W1[0..5] -> next W2[0]
  half8 wf[2][8];
  #define LOADT(P, BASE, NT) { _Pragma("unroll") \
    for (int _ks = 0; _ks < 8; ++_ks) \
      wf[P][_ks] = *(const half8*)((BASE) + (size_t)(NT) * 4096 + _ks * 512); }

  LOADT(0, w2b, 0)

  for (int lt = 0; lt < Tc; ++lt) {
    const int gt = t0 + lt;
    const int rp = (gt & 1) ^ 1;
    const int wp = gt & 1;

    // ======== PHASE 1 ========
    const _Float16* xb = Xw + ((((size_t)lt * NBG + bg) * 48 + wave * 6) * 256)
                         + lc * 16 + lq * 4;
    half4 xwv[6];
    #pragma unroll
    for (int nt = 0; nt < 6; ++nt) xwv[nt] = *(const half4*)(xb + nt * 256);

    floatx4 ag1[6], ag0[6], av = splat4(pb);
    #pragma unroll
    for (int nt = 0; nt < 6; ++nt) {
      ag1[nt] = splat4(bh1c[nt / 3][nt % 3]);
      ag0[nt] = splat4(bh0c[nt / 3][nt % 3]);
    }

    {  // h1(t-1): v-pre + gh1 (W2 stream, tiles 0..5)
      half8 A1f[8];
      #pragma unroll
      for (int ks = 0; ks < 8; ++ks) A1f[ks] = LDA(1, rp, ks);
      #pragma unroll
      for (int ks = 0; ks < 8; ++ks)
        av = __builtin_amdgcn_mfma_f32_16x16x32_f16(A1f[ks], Pj[ks], av, 0, 0, 0);
      #pragma unroll
      for (int nt = 0; nt < 6; ++nt) {
        if (nt < 5) { LOADT((nt + 1) & 1, w2b, nt + 1) } else { LOADT(0, w0b, 0) }
        #pragma unroll
        for (int ks = 0; ks < 8; ++ks)
          ag1[nt] = __builtin_amdgcn_mfma_f32_16x16x32_f16(A1f[ks], wf[nt & 1][ks], ag1[nt], 0, 0, 0);
      }
    }
    {  // h0(t-1): gh0 (W0 stream, tiles 6..11)
      half8 A0f[8];
      #pragma unroll
      for (int ks = 0; ks < 8; ++ks) A0f[ks] = LDA(0, rp, ks);
      #pragma unroll
      for (int nt = 0; nt < 6; ++nt) {
        if (nt < 5) { LOADT((nt + 1) & 1, w0b, nt + 1) } else { LOADT(0, w1b, 0) }
        #pragma unroll
        for (int ks = 0; ks < 8; ++ks)
          ag0[nt] = __builtin_amdgcn_mfma_f32_16x16x32_f16(A0f[ks], wf[nt & 1][ks], ag0[nt], 0, 0, 0);
      }
    }

    // v(t-1): sigmoid, output write, wave-local redistribution
    float vv0[4], vv1[4], vv2[4];
    if (gt == 0) {
      #pragma unroll
      for (int q = 0; q < 4; ++q) { vv0[q] = 0.f; vv1[q] = 0.f; vv2[q] = 0.f; }
    } else {
      float sv[4];
      #pragma unroll
      for (int q = 0; q < 4; ++q) sv[q] = (lc < 3) ? sigmoidf_(av[q]) : 0.f;
      if (wave == 0 && lc < 3) {
        #pragma unroll
        for (int q = 0; q < 4; ++q)
          out[((size_t)(bg * 16 + lq * 4 + q) * T_FULL + (gt - 1)) * ODIM + lc] = sv[q];
      }
      #pragma unroll
      for (int q = 0; q < 4; ++q) {
        vv0[q] = __shfl(sv[q], (lq << 4) + 0, 64);
        vv1[q] = __shfl(sv[q], (lq << 4) + 1, 64);
        vv2[q] = __shfl(sv[q], (lq << 4) + 2, 64);
      }
    }

    // layer-0 combine, publish h0(t)
    #pragma unroll
    for (int ct = 0; ct < 2; ++ct)
      #pragma unroll
      for (int q = 0; q < 4; ++q) {
        const float ir = (float)xwv[ct * 3 + 0][q] + wcb[ct][0][3]
                         + vv0[q] * wcb[ct][0][0] + vv1[q] * wcb[ct][0][1] + vv2[q] * wcb[ct][0][2];
        const float iz = (float)xwv[ct * 3 + 1][q] + wcb[ct][1][3]
                         + vv0[q] * wcb[ct][1][0] + vv1[q] * wcb[ct][1][1] + vv2[q] * wcb[ct][1][2];
        const float in_ = (float)xwv[ct * 3 + 2][q] + wcb[ct][2][3]
                         + vv0[q] * wcb[ct][2][0] + vv1[q] * wcb[ct][2][1] + vv2[q] * wcb[ct][2][2];
        const float r = sigmoidf_(ir + ag0[ct * 3 + 0][q]);
        const float z = sigmoidf_(iz + ag0[ct * 3 + 1][q]);
        const float n = tanhf_(in_ + r * ag0[ct * 3 + 2][q]);
        const float h0n = (1.f - z) * n + z * h0st[ct][q];
        h0st[ct][q] = h0n;
        *(_Float16*)((char*)(&hl[0][wp][0]) + HBYTE(lq * 4 + q, ch[ct])) = (_Float16)h0n;
      }
    __syncthreads();   // barrier 1: h0(t) visible

    // ======== PHASE 2 ========  (W1 stream, tiles 12..17; tile 12 prefetched)
    floatx4 ai[6];
    #pragma unroll
    for (int nt = 0; nt < 6; ++nt) ai[nt] = splat4(bi1c[nt / 3][nt % 3]);
    {
      half8 A0n[8];
      #pragma unroll
      for (int ks = 0; ks < 8; ++ks) A0n[ks] = LDA(0, wp, ks);
      #pragma unroll
      for (int nt = 0; nt < 6; ++nt) {
        if (nt < 5) { LOADT((nt + 1) & 1, w1b, nt + 1) } else { LOADT(0, w2b, 0) } // chain next step
        #pragma unroll
        for (int ks = 0; ks < 8; ++ks)
          ai[nt] = __builtin_amdgcn_mfma_f32_16x16x32_f16(A0n[ks], wf[nt & 1][ks], ai[nt], 0, 0, 0);
      }
    }

    #pragma unroll
    for (int ct = 0; ct < 2; ++ct)
      #pragma unroll
      for (int q = 0; q < 4; ++q) {
        const float r = sigmoidf_(ai[ct * 3 + 0][q] + ag1[ct * 3 + 0][q]);
        const float z = sigmoidf_(ai[ct * 3 + 1][q] + ag1[ct * 3 + 1][q]);
        const float n = tanhf_(ai[ct * 3 + 2][q] + r * ag1[ct * 3 + 2][q]);
        const float h1n = (1.f - z) * n + z * h1st[ct][q];
        h1st[ct][q] = h1n;
        *(_Float16*)((char*)(&hl[1][wp][0]) + HBYTE(lq * 4 + q, ch[ct])) = (_Float16)h1n;
      }
    __syncthreads();   // barrier 2: h1(t) visible for next step
  }

  // tail: v(T-1) from final h1
  if (lastChunk) {
    const int fp = (t0 + Tc - 1) & 1;
    floatx4 av = splat4(pb);
    #pragma unroll
    for (int ks = 0; ks < 8; ++ks)
      av = __builtin_amdgcn_mfma_f32_16x16x32_f16(LDA(1, fp, ks), Pj[ks], av, 0, 0, 0);
    if (wave == 0 && lc < 3) {
      #pragma unroll
      for (int q = 0; q < 4; ++q)
        out[((size_t)(bg * 16 + lq * 4 + q) * T_FULL + (T_FULL - 1)) * ODIM + lc]
            = sigmoidf_(av[q]);
    }
  }

  // save state for next chunk (kernel boundary = coherent)
  #pragma unroll
  for (int ct = 0; ct < 2; ++ct)
    #pragma unroll
    for (int q = 0; q < 4; ++q) {
      hs[((size_t)(bg * 2 + 0) * 16 + lq * 4 + q) * NCH + ch[ct]] = h0st[ct][q];
      hs[((size_t)(bg * 2 + 1) * 16 + lq * 4 + q) * NCH + ch[ct]] = h1st[ct][q];
    }
  #undef HBYTE
  #undef LDA
  #undef LOADT
}

extern "C" void kernel_launch(void* const* d_in, const int* in_sizes, int n_in,
                              void* d_out, int out_size, void* d_ws, size_t ws_size,
                              hipStream_t stream) {
  const float* x       = (const float*)d_in[0];
  const float* embed_w = (const float*)d_in[1];
  const float* embed_b = (const float*)d_in[2];
  const float* w_ih0   = (const float*)d_in[3];
  const float* w_hh0   = (const float*)d_in[4];
  const float* b_ih0   = (const float*)d_in[5];
  const float* b_hh0   = (const float*)d_in[6];
  const float* w_ih1   = (const float*)d_in[7];
  const float* w_hh1   = (const float*)d_in[8];
  const float* b_ih1   = (const float*)d_in[9];
  const float* b_hh1   = (const float*)d_in[10];
  const float* proj_w  = (const float*)d_in[11];
  const float* proj_b  = (const float*)d_in[12];
  float* out = (float*)d_out;

  char* ws = (char*)d_ws;
  _Float16* Wp  = (_Float16*)ws;
  _Float16* Pp  = (_Float16*)(ws + PP_OFF);
  float*    Wcb = (float*)(ws + WCB_OFF);
  float*    hs  = (float*)(ws + HS_OFF);
  _Float16* Xw  = (_Float16*)(ws + XW_OFF);

  wprep_w<<<290, 256, 0, stream>>>(w_hh0, w_ih1, w_hh1, proj_w, Wp, Pp);
  wprep_c<<<3, 256, 0, stream>>>(w_ih0, embed_w, embed_b, b_ih0, Wcb);

  const size_t per_t = (size_t)NBATCH * GD * sizeof(_Float16);  // 98304 B
  size_t xw_avail = (ws_size > XW_OFF) ? (ws_size - XW_OFF) : 0;
  long maxTc = (long)(xw_avail / per_t);
  int Tc = 2;
  while ((long)Tc * 2 <= maxTc && Tc * 2 <= T_FULL) Tc *= 2;

  for (int t0 = 0; t0 < T_FULL; t0 += Tc) {
    dim3 g1(Tc * NBATCH / 128, GD / 128);
    xw_gemm<<<g1, 256, 0, stream>>>(x, w_ih0, Xw, t0, Tc);
    rec_s<<<NBG, 512, 0, stream>>>(Wp, Pp, Wcb, b_hh0, b_ih1, b_hh1, proj_b,
                                   Xw, out, hs, t0, Tc,
                                   (t0 + Tc) >= T_FULL ? 1 : 0);
  }
}